// Round 7
// baseline (399.058 us; speedup 1.0000x reference)
//
#include <hip/hip_runtime.h>
#include <math.h>

#define NB 4096
#define DX 1024
#define DZ 128
#define KNN 10
#define STR 32
#define NLIST 32         /* one merged list per row per strip */
#define BKK 64           /* kNN K-tile */

typedef short short8v __attribute__((ext_vector_type(8)));
typedef float f32x4 __attribute__((ext_vector_type(4)));

#define MFMA16(a, b, c) __builtin_amdgcn_mfma_f32_16x16x32_bf16((a), (b), (c), 0, 0, 0)

__device__ __forceinline__ ushort f2bf(float f) {
  unsigned u = __float_as_uint(f);
  u += 0x7FFFu + ((u >> 16) & 1u);
  return (ushort)(u >> 16);
}
__device__ __forceinline__ float bf2f(ushort h) {
  return __uint_as_float(((unsigned)h) << 16);
}

// k_zr (BK=32, 64B rows) swizzled fragment load
__device__ __forceinline__ short8v frag_ld(const ushort* base, int row, int fg) {
  int off = (row << 6) + (fg << 4);
  off ^= (row & 7) << 4;
  return *(const short8v*)((const char*)base + off);
}

// kNN (BK=64, 128B rows): slot-permutation swizzle, pure within-row bijection
__device__ __forceinline__ int swz64(int row, int c8) {
  return (row << 7) + ((c8 ^ (row & 7)) << 4);
}
__device__ __forceinline__ short8v frag_ld64(const ushort* base, int row, int kk, int fg) {
  return *(const short8v*)((const char*)base + swz64(row, kk * 4 + fg));
}

// branchless register top-10 insert (all indices static after unroll)
#define INSERT10(td, ti, v, idx)                         \
  do {                                                   \
    if ((v) < td[KNN - 1]) {                             \
      _Pragma("unroll")                                  \
      for (int k_ = KNN - 1; k_ >= 1; --k_) {            \
        bool bk = (v) < td[k_];                          \
        bool bk1 = (v) < td[k_ - 1];                     \
        td[k_] = bk ? (bk1 ? td[k_ - 1] : (v)) : td[k_]; \
        ti[k_] = bk ? (bk1 ? ti[k_ - 1] : (idx)) : ti[k_]; \
      }                                                  \
      bool b0 = (v) < td[0];                             \
      ti[0] = b0 ? (idx) : ti[0];                        \
      td[0] = b0 ? (v) : td[0];                          \
    }                                                    \
  } while (0)

// ---------------- row sum of squares (fallback path only) ----------------
__global__ __launch_bounds__(256) void k_rowsq(const float* __restrict__ a,
                                               float* __restrict__ out, int D) {
  int row = blockIdx.x;
  const float4* p = (const float4*)(a + (size_t)row * D);
  float s = 0.f;
  for (int d = threadIdx.x; d < (D >> 2); d += 256) {
    float4 v = p[d];
    s = fmaf(v.x, v.x, s); s = fmaf(v.y, v.y, s);
    s = fmaf(v.z, v.z, s); s = fmaf(v.w, v.w, s);
  }
#pragma unroll
  for (int m = 32; m; m >>= 1) s += __shfl_xor(s, m);
  __shared__ float red[4];
  int w = threadIdx.x >> 6;
  if ((threadIdx.x & 63) == 0) red[w] = s;
  __syncthreads();
  if (threadIdx.x == 0) out[row] = red[0] + red[1] + red[2] + red[3];
}

// ---------------- fused prep for x: bf16-hi split + row sumsq ----------------
__global__ __launch_bounds__(256) void k_prep_x(const float* __restrict__ x,
                                                ushort* __restrict__ xh,
                                                float* __restrict__ sqx) {
  const int row = blockIdx.x, t = threadIdx.x;
  float4 v = ((const float4*)(x + (size_t)row * DX))[t];
  ushort4 hv;
  hv.x = f2bf(v.x); hv.y = f2bf(v.y); hv.z = f2bf(v.z); hv.w = f2bf(v.w);
  ((ushort4*)(xh + (size_t)row * DX))[t] = hv;
  float s = fmaf(v.x, v.x, fmaf(v.y, v.y, fmaf(v.z, v.z, v.w * v.w)));
#pragma unroll
  for (int m = 32; m; m >>= 1) s += __shfl_xor(s, m);
  __shared__ float red[4];
  int w = t >> 6;
  if ((t & 63) == 0) red[w] = s;
  __syncthreads();
  if (t == 0) sqx[row] = red[0] + red[1] + red[2] + red[3];
}

// ---------------- fused prep for z/ref: hi/lo split + row sumsq ----------------
// 1024 elems per block = 8 rows of 128; 32 consecutive threads = one row
__global__ __launch_bounds__(256) void k_prep_zr(const float* __restrict__ z,
                                                 const float* __restrict__ rfm,
                                                 ushort* __restrict__ zh, ushort* __restrict__ zl,
                                                 ushort* __restrict__ rh, ushort* __restrict__ rl,
                                                 float* __restrict__ sqz, float* __restrict__ sqr) {
  const float* src = blockIdx.y ? rfm : z;
  ushort* ph = blockIdx.y ? rh : zh;
  ushort* pl = blockIdx.y ? rl : zl;
  float* sq = blockIdx.y ? sqr : sqz;
  const int t = threadIdx.x;
  const size_t base = (size_t)blockIdx.x * 1024;
  float4 v = ((const float4*)(src + base))[t];
  float vv[4] = {v.x, v.y, v.z, v.w};
  ushort h[4], l[4];
#pragma unroll
  for (int e = 0; e < 4; ++e) {
    h[e] = f2bf(vv[e]);
    l[e] = f2bf(vv[e] - bf2f(h[e]));
  }
  ushort4 hv; hv.x = h[0]; hv.y = h[1]; hv.z = h[2]; hv.w = h[3];
  ushort4 lv; lv.x = l[0]; lv.y = l[1]; lv.z = l[2]; lv.w = l[3];
  ((ushort4*)(ph + base))[t] = hv;
  ((ushort4*)(pl + base))[t] = lv;
  float s = fmaf(v.x, v.x, fmaf(v.y, v.y, fmaf(v.z, v.z, v.w * v.w)));
#pragma unroll
  for (int m = 16; m; m >>= 1) s += __shfl_xor(s, m);   // within 32-lane row group
  if ((t & 31) == 0) sq[blockIdx.x * 8 + (t >> 5)] = s;
}

// ---------------- kNN via MFMA: one 128x128 tile per block, reg-pipelined ----------------
struct SmemKNN {
  union {
    struct { ushort Ah[128 * BKK], Bh[128 * BKK]; } s;  // 16+16 KB
    float D[64 * 129];                                  // 33 KB (chunked)
  } u;
};

template<int PRE>
__global__ __launch_bounds__(256, 4) void k_knn(const float* __restrict__ x,
                                                const ushort* __restrict__ xh,
                                                const float* __restrict__ sqx,
                                                float* __restrict__ cand_d,
                                                int* __restrict__ cand_i) {
  __shared__ SmemKNN sm;
  // bijective 2D XCD swizzle: each XCD owns an 8-strip x 16-itile rectangle
  const int bid = blockIdx.y * STR + blockIdx.x;
  const int xcd = bid & 7, rr = bid >> 3;
  const int strip = (xcd & 3) * 8 + (rr & 7);
  const int itile = (xcd >> 2) * 16 + (rr >> 3);
  const int i0 = itile * 128;
  const int j0 = strip * 128;

  const int tid = threadIdx.x;
  const int lane = tid & 63, wv = tid >> 6;
  const int wr = wv >> 1, wc = wv & 1;
  const int fr = lane & 15, fg = lane >> 4;

  float td[KNN];
  int ti[KNN];
#pragma unroll
  for (int k = 0; k < KNN; ++k) { td[k] = 3.0e38f; ti[k] = 0; }
  const int my_chunk = tid >> 7;
  const int t2 = tid & 127;
  const int srow = t2 >> 1;
  const int cbase = (tid & 1) * 64;

  f32x4 acc[4][4];
  const f32x4 zv4 = {0.f, 0.f, 0.f, 0.f};
#pragma unroll
  for (int m = 0; m < 4; ++m)
#pragma unroll
    for (int n = 0; n < 4; ++n) acc[m][n] = zv4;

  if (PRE) {
    uint4 ra[4], rb[4];
#define KLOAD(kc)                                                            \
  _Pragma("unroll")                                                          \
  for (int l = 0; l < 4; ++l) {                                              \
    int idx = tid + l * 256;                                                 \
    int row = idx >> 3, c8 = idx & 7;                                        \
    ra[l] = *(const uint4*)(xh + (size_t)(i0 + row) * DX + (kc) + c8 * 8);   \
    rb[l] = *(const uint4*)(xh + (size_t)(j0 + row) * DX + (kc) + c8 * 8);   \
  }
#define KSTORE()                                                             \
  _Pragma("unroll")                                                          \
  for (int l = 0; l < 4; ++l) {                                              \
    int idx = tid + l * 256;                                                 \
    int row = idx >> 3, c8 = idx & 7;                                        \
    int off = swz64(row, c8);                                                \
    *(uint4*)((char*)sm.u.s.Ah + off) = ra[l];                               \
    *(uint4*)((char*)sm.u.s.Bh + off) = rb[l];                               \
  }
    KLOAD(0);
    for (int kc = 0; kc < DX; kc += BKK) {
      __syncthreads();
      KSTORE();
      __syncthreads();
      if (kc + BKK < DX) KLOAD(kc + BKK);   // next tile in flight under MFMA
#pragma unroll
      for (int kk = 0; kk < 2; ++kk) {
        short8v fa[4];
#pragma unroll
        for (int m = 0; m < 4; ++m)
          fa[m] = frag_ld64(sm.u.s.Ah, wr * 64 + m * 16 + fr, kk, fg);
#pragma unroll
        for (int n = 0; n < 4; ++n) {
          short8v fb = frag_ld64(sm.u.s.Bh, wc * 64 + n * 16 + fr, kk, fg);
#pragma unroll
          for (int m = 0; m < 4; ++m)
            acc[m][n] = MFMA16(fa[m], fb, acc[m][n]);
        }
      }
    }
#undef KLOAD
#undef KSTORE
  } else {
    for (int kc = 0; kc < DX; kc += BKK) {
      __syncthreads();
#pragma unroll
      for (int l = 0; l < 4; ++l) {
        int idx = tid + l * 256;
        int row = idx >> 3, c8 = idx & 7;
        int off = swz64(row, c8);
        const float* pa = &x[(size_t)(i0 + row) * DX + kc + c8 * 8];
        const float* pb = &x[(size_t)(j0 + row) * DX + kc + c8 * 8];
        float4 a1 = *(const float4*)pa, a2 = *(const float4*)(pa + 4);
        float4 b1 = *(const float4*)pb, b2 = *(const float4*)(pb + 4);
        uint4 pva, pvb;
        pva.x = (unsigned)f2bf(a1.x) | ((unsigned)f2bf(a1.y) << 16);
        pva.y = (unsigned)f2bf(a1.z) | ((unsigned)f2bf(a1.w) << 16);
        pva.z = (unsigned)f2bf(a2.x) | ((unsigned)f2bf(a2.y) << 16);
        pva.w = (unsigned)f2bf(a2.z) | ((unsigned)f2bf(a2.w) << 16);
        pvb.x = (unsigned)f2bf(b1.x) | ((unsigned)f2bf(b1.y) << 16);
        pvb.y = (unsigned)f2bf(b1.z) | ((unsigned)f2bf(b1.w) << 16);
        pvb.z = (unsigned)f2bf(b2.x) | ((unsigned)f2bf(b2.y) << 16);
        pvb.w = (unsigned)f2bf(b2.z) | ((unsigned)f2bf(b2.w) << 16);
        *(uint4*)((char*)sm.u.s.Ah + off) = pva;
        *(uint4*)((char*)sm.u.s.Bh + off) = pvb;
      }
      __syncthreads();
#pragma unroll
      for (int kk = 0; kk < 2; ++kk) {
        short8v fa[4];
#pragma unroll
        for (int m = 0; m < 4; ++m)
          fa[m] = frag_ld64(sm.u.s.Ah, wr * 64 + m * 16 + fr, kk, fg);
#pragma unroll
        for (int n = 0; n < 4; ++n) {
          short8v fb = frag_ld64(sm.u.s.Bh, wc * 64 + n * 16 + fr, kk, fg);
#pragma unroll
          for (int m = 0; m < 4; ++m)
            acc[m][n] = MFMA16(fa[m], fb, acc[m][n]);
        }
      }
    }
  }
  __syncthreads();
  // chunked epilogue: two 64-row passes through the 33 KB D buffer
#pragma unroll
  for (int chunk = 0; chunk < 2; ++chunk) {
    if (wr == chunk) {
#pragma unroll
      for (int m = 0; m < 4; ++m)
#pragma unroll
        for (int n = 0; n < 4; ++n)
#pragma unroll
          for (int r = 0; r < 4; ++r) {
            int rl = m * 16 + fg * 4 + r;
            int cl = wc * 64 + n * 16 + fr;
            int gi = i0 + chunk * 64 + rl, gj = j0 + cl;
            float v = sqx[gi] + sqx[gj] - 2.f * acc[m][n][r];
            sm.u.D[rl * 129 + cl] = (gi == gj) ? 3.0e38f : v;
          }
    }
    __syncthreads();
    if (my_chunk == chunk) {
#pragma unroll 4
      for (int c = 0; c < 64; ++c) {
        float v = sm.u.D[srow * 129 + cbase + c];
        int idx = j0 + cbase + c;
        INSERT10(td, ti, v, idx);
      }
    }
    __syncthreads();
  }
  // pair-merge the two half-row lists via shuffle (snapshot first!)
  {
    float pd[KNN]; int pi[KNN];
#pragma unroll
    for (int l = 0; l < KNN; ++l) {
      pd[l] = __shfl_xor(td[l], 1);
      pi[l] = __shfl_xor(ti[l], 1);
    }
#pragma unroll
    for (int l = 0; l < KNN; ++l) INSERT10(td, ti, pd[l], pi[l]);
    if ((tid & 1) == 0) {
      int row = i0 + my_chunk * 64 + srow;
#pragma unroll
      for (int l = 0; l < KNN; ++l) {
        cand_d[((size_t)row * NLIST + strip) * KNN + l] = td[l];
        cand_i[((size_t)row * NLIST + strip) * KNN + l] = ti[l];
      }
    }
  }
}

// ---------------- merge: one WAVE per row, butterfly argmin extraction ----------------
__global__ __launch_bounds__(256) void k_merge(const float* __restrict__ cand_d,
                                               const int* __restrict__ cand_i,
                                               int* __restrict__ knn) {
  const int lane = threadIdx.x & 63;
  const int row = blockIdx.x * 4 + (threadIdx.x >> 6);
  float v[KNN]; int jx[KNN];
  const float* cd = cand_d + ((size_t)row * NLIST + lane) * KNN;
  const int* ci = cand_i + ((size_t)row * NLIST + lane) * KNN;
  const bool act = lane < NLIST;
#pragma unroll
  for (int l = 0; l < KNN; ++l) {
    v[l] = act ? cd[l] : 3.0e38f;
    jx[l] = act ? ci[l] : 0;
  }
#pragma unroll
  for (int k = 0; k < KNN; ++k) {
    float bv = v[0]; int bj = jx[0]; int bl = lane;
#pragma unroll
    for (int m = 1; m < 64; m <<= 1) {
      float ov = __shfl_xor(bv, m);
      int oj = __shfl_xor(bj, m);
      int ol = __shfl_xor(bl, m);
      bool take = ov < bv;
      bv = take ? ov : bv; bj = take ? oj : bj; bl = take ? ol : bl;
    }
    if (lane == 0) knn[row * KNN + k] = bj;
    if (lane == bl) {
#pragma unroll
      for (int l = 0; l < KNN - 1; ++l) { v[l] = v[l + 1]; jx[l] = jx[l + 1]; }
      v[KNN - 1] = 3.0e38f;
    }
  }
}

// ---------------- Gram matrix of centered neighbors (one wave / point) ----
__global__ __launch_bounds__(64) void k_gram(const float* __restrict__ x,
                                             const int* __restrict__ knn,
                                             float* __restrict__ G) {
  const int pt = blockIdx.x;
  const int lane = threadIdx.x;
  const float4* nb[KNN];
#pragma unroll
  for (int a = 0; a < KNN; ++a)
    nb[a] = (const float4*)(x + (size_t)knn[pt * KNN + a] * DX);
  float P[55];
  float U[KNN];
  float q = 0.f;
#pragma unroll
  for (int c = 0; c < 55; ++c) P[c] = 0.f;
#pragma unroll
  for (int a = 0; a < KNN; ++a) U[a] = 0.f;
  for (int d4 = lane; d4 < DX / 4; d4 += 64) {
    float4 n4[KNN];
#pragma unroll
    for (int a = 0; a < KNN; ++a) n4[a] = nb[a][d4];
#pragma unroll
    for (int e = 0; e < 4; ++e) {
      float n[KNN];
#pragma unroll
      for (int a = 0; a < KNN; ++a) n[a] = ((const float*)&n4[a])[e];
      float m = 0.f;
#pragma unroll
      for (int a = 0; a < KNN; ++a) m += n[a];
      m *= 0.1f;
      q = fmaf(m, m, q);
#pragma unroll
      for (int a = 0; a < KNN; ++a) U[a] = fmaf(n[a], m, U[a]);
      int c = 0;
#pragma unroll
      for (int a = 0; a < KNN; ++a)
#pragma unroll
        for (int b = a; b < KNN; ++b) { P[c] = fmaf(n[a], n[b], P[c]); ++c; }
    }
  }
#pragma unroll
  for (int c = 0; c < 55; ++c)
#pragma unroll
    for (int m2 = 32; m2; m2 >>= 1) P[c] += __shfl_xor(P[c], m2);
#pragma unroll
  for (int a = 0; a < KNN; ++a)
#pragma unroll
    for (int m2 = 32; m2; m2 >>= 1) U[a] += __shfl_xor(U[a], m2);
#pragma unroll
  for (int m2 = 32; m2; m2 >>= 1) q += __shfl_xor(q, m2);
  if (lane == 0) {
    int c = 0;
    for (int a = 0; a < KNN; ++a)
      for (int b = a; b < KNN; ++b) { G[(size_t)pt * 55 + c] = P[c] - U[a] - U[b] + q; ++c; }
  }
}

// ---------------- Jacobi eigenvalues of 10x10 in registers ---------------
// Tournament (round-robin) ordering: 9 rounds x 5 DISJOINT pairs per sweep.
// Disjoint rotations commute exactly -> still cyclic Jacobi; ILP ~5.
__device__ __forceinline__ constexpr int IJ(int a, int b) {
  return (a <= b) ? (10 * a - (a * (a - 1)) / 2 + (b - a))
                  : (10 * b - (b * (b - 1)) / 2 + (a - b));
}

#define ROTPQ(p, q)                                                  \
  {                                                                  \
    float apq = M[IJ((p), (q))];                                     \
    float app = M[IJ((p), (p))], aqq = M[IJ((q), (q))];              \
    float theta = (aqq - app) / (2.f * apq);                         \
    float t = 1.f / (fabsf(theta) + sqrtf(fmaf(theta, theta, 1.f))); \
    t = (theta < 0.f) ? -t : t;                                      \
    t = (apq == 0.f) ? 0.f : t;                                      \
    float cc = 1.f / sqrtf(fmaf(t, t, 1.f));                         \
    float ss = t * cc;                                               \
    _Pragma("unroll")                                                \
    for (int r_ = 0; r_ < KNN; ++r_) {                               \
      if (r_ == (p) || r_ == (q)) continue;                          \
      float vrp = M[IJ(r_, (p))];                                    \
      float vrq = M[IJ(r_, (q))];                                    \
      M[IJ(r_, (p))] = cc * vrp - ss * vrq;                          \
      M[IJ(r_, (q))] = ss * vrp + cc * vrq;                          \
    }                                                                \
    M[IJ((p), (p))] = app - t * apq;                                 \
    M[IJ((q), (q))] = aqq + t * apq;                                 \
    M[IJ((p), (q))] = 0.f;                                           \
  }

#define NSWEEP 7
__global__ __launch_bounds__(64) void k_jacobi(const float* __restrict__ G,
                                               float* __restrict__ curv) {
  const int pt = blockIdx.x * 64 + threadIdx.x;
  float M[55];
#pragma unroll
  for (int c = 0; c < 55; ++c) M[c] = G[(size_t)pt * 55 + c];

#pragma unroll
  for (int sweep = 0; sweep < NSWEEP; ++sweep) {
#pragma unroll
    for (int rd = 0; rd < 9; ++rd) {
      ROTPQ(9, rd);
      ROTPQ((rd + 1) % 9, (rd + 8) % 9);
      ROTPQ((rd + 2) % 9, (rd + 7) % 9);
      ROTPQ((rd + 3) % 9, (rd + 6) % 9);
      ROTPQ((rd + 4) % 9, (rd + 5) % 9);
    }
  }

  float lmax = 0.f, ssum = 0.f;
#pragma unroll
  for (int a = 0; a < KNN; ++a) {
    float l = fmaxf(M[IJ(a, a)], 0.f);
    lmax = fmaxf(lmax, l);
    ssum += sqrtf(l);
  }
  curv[pt] = 1.f - sqrtf(lmax) / (ssum + 1e-8f);
}

// ---------------- fused z/ref upper-triangle pass (MFMA, hi+lo) ----------------
template<int PRE>
__global__ __launch_bounds__(256, 2) void k_zr(const float* __restrict__ z,
                                               const float* __restrict__ rfm,
                                               const ushort* __restrict__ zh,
                                               const ushort* __restrict__ zl,
                                               const ushort* __restrict__ rh,
                                               const ushort* __restrict__ rl,
                                               const float* __restrict__ sqz,
                                               const float* __restrict__ sqr,
                                               const float* __restrict__ curv,
                                               double* __restrict__ pS,
                                               float* __restrict__ pM) {
  __shared__ struct { ushort Ah[4096], Al[4096], Bh[4096], Bl[4096]; } s;
  const int t = blockIdx.x;
  int ib = 0, base = 0;
  while (base + (32 - ib) <= t) { base += 32 - ib; ++ib; }
  const int jb = ib + (t - base);
  const int i0 = ib * 128, j0 = jb * 128;
  const int tid = threadIdx.x;
  const int lane = tid & 63, wv = tid >> 6;
  const int wr = wv >> 1, wc = wv & 1;
  const int fr = lane & 15, fg = lane >> 4;

  f32x4 zacc[4][4], racc[4][4];
  const f32x4 zv = {0.f, 0.f, 0.f, 0.f};
#pragma unroll
  for (int m = 0; m < 4; ++m)
#pragma unroll
    for (int n = 0; n < 4; ++n) { zacc[m][n] = zv; racc[m][n] = zv; }

#pragma unroll
  for (int mat = 0; mat < 2; ++mat) {
    const float* P = mat ? rfm : z;
    const ushort* Ph = mat ? rh : zh;
    const ushort* Pl = mat ? rl : zl;
    for (int kc = 0; kc < DZ; kc += 32) {
      __syncthreads();
      if (PRE) {
#pragma unroll
        for (int l = 0; l < 2; ++l) {
          int idx = tid + l * 256;
          int row = idx >> 2, c8 = idx & 3;
          int off = (row << 6) + (c8 << 4);
          off ^= (row & 7) << 4;
          size_t ga = (size_t)(i0 + row) * DZ + kc + c8 * 8;
          size_t gb = (size_t)(j0 + row) * DZ + kc + c8 * 8;
          *(uint4*)((char*)s.Ah + off) = *(const uint4*)(Ph + ga);
          *(uint4*)((char*)s.Al + off) = *(const uint4*)(Pl + ga);
          *(uint4*)((char*)s.Bh + off) = *(const uint4*)(Ph + gb);
          *(uint4*)((char*)s.Bl + off) = *(const uint4*)(Pl + gb);
        }
      } else {
#pragma unroll
        for (int l = 0; l < 4; ++l) {
          int idx = tid + l * 256;
          int row = idx >> 3, c4 = idx & 7;
          int off = (row << 6) + (c4 << 3);
          off ^= (row & 7) << 4;
          float4 va = *(const float4*)&P[(size_t)(i0 + row) * DZ + kc + c4 * 4];
          float4 vb = *(const float4*)&P[(size_t)(j0 + row) * DZ + kc + c4 * 4];
          float av[4] = {va.x, va.y, va.z, va.w};
          float bv[4] = {vb.x, vb.y, vb.z, vb.w};
          ushort ah4[4], al4[4], bh4[4], bl4[4];
#pragma unroll
          for (int e = 0; e < 4; ++e) {
            ah4[e] = f2bf(av[e]); al4[e] = f2bf(av[e] - bf2f(ah4[e]));
            bh4[e] = f2bf(bv[e]); bl4[e] = f2bf(bv[e] - bf2f(bh4[e]));
          }
          uint2 p;
          p.x = (unsigned)ah4[0] | ((unsigned)ah4[1] << 16);
          p.y = (unsigned)ah4[2] | ((unsigned)ah4[3] << 16);
          *(uint2*)((char*)s.Ah + off) = p;
          p.x = (unsigned)al4[0] | ((unsigned)al4[1] << 16);
          p.y = (unsigned)al4[2] | ((unsigned)al4[3] << 16);
          *(uint2*)((char*)s.Al + off) = p;
          p.x = (unsigned)bh4[0] | ((unsigned)bh4[1] << 16);
          p.y = (unsigned)bh4[2] | ((unsigned)bh4[3] << 16);
          *(uint2*)((char*)s.Bh + off) = p;
          p.x = (unsigned)bl4[0] | ((unsigned)bl4[1] << 16);
          p.y = (unsigned)bl4[2] | ((unsigned)bl4[3] << 16);
          *(uint2*)((char*)s.Bl + off) = p;
        }
      }
      __syncthreads();
      short8v fah[4], fal[4];
#pragma unroll
      for (int m = 0; m < 4; ++m) {
        int r = wr * 64 + m * 16 + fr;
        fah[m] = frag_ld(s.Ah, r, fg);
        fal[m] = frag_ld(s.Al, r, fg);
      }
#pragma unroll
      for (int n = 0; n < 4; ++n) {
        int r = wc * 64 + n * 16 + fr;
        short8v fbh = frag_ld(s.Bh, r, fg);
        short8v fbl = frag_ld(s.Bl, r, fg);
#pragma unroll
        for (int m = 0; m < 4; ++m) {
          if (mat == 0) {
            zacc[m][n] = MFMA16(fah[m], fbh, zacc[m][n]);
            zacc[m][n] = MFMA16(fah[m], fbl, zacc[m][n]);
            zacc[m][n] = MFMA16(fal[m], fbh, zacc[m][n]);
          } else {
            racc[m][n] = MFMA16(fah[m], fbh, racc[m][n]);
            racc[m][n] = MFMA16(fah[m], fbl, racc[m][n]);
            racc[m][n] = MFMA16(fal[m], fbh, racc[m][n]);
          }
        }
      }
    }
  }

  double s1 = 0, s2 = 0, s3 = 0;
  float mz = 0.f, mr = 0.f;
#pragma unroll
  for (int m = 0; m < 4; ++m)
#pragma unroll
    for (int n = 0; n < 4; ++n)
#pragma unroll
      for (int r = 0; r < 4; ++r) {
        int gi = i0 + wr * 64 + m * 16 + fg * 4 + r;
        int gj = j0 + wc * 64 + n * 16 + fr;
        if (gj > gi) {
          float z2 = fmaxf(sqz[gi] + sqz[gj] - 2.f * zacc[m][n][r], 0.f);
          float r2 = fmaxf(sqr[gi] + sqr[gj] - 2.f * racc[m][n][r], 0.f);
          float w = fmaxf(1.f - fmaxf(curv[gi], curv[gj]), 0.1f);
          s1 += (double)(w * z2);
          s3 += (double)(w * r2);
          s2 += (double)(w * sqrtf(z2 * r2));
          mz = fmaxf(mz, z2);
          mr = fmaxf(mr, r2);
        }
      }
#pragma unroll
  for (int m = 32; m; m >>= 1) {
    s1 += __shfl_xor(s1, m);
    s2 += __shfl_xor(s2, m);
    s3 += __shfl_xor(s3, m);
    mz = fmaxf(mz, __shfl_xor(mz, m));
    mr = fmaxf(mr, __shfl_xor(mr, m));
  }
  __shared__ double rd[4][3];
  __shared__ float rf2[4][2];
  int w = tid >> 6;
  if ((tid & 63) == 0) { rd[w][0] = s1; rd[w][1] = s2; rd[w][2] = s3; rf2[w][0] = mz; rf2[w][1] = mr; }
  __syncthreads();
  if (tid == 0) {
    double a = 0, b = 0, c = 0; float d = 0.f, e = 0.f;
    for (int i = 0; i < 4; ++i) {
      a += rd[i][0]; b += rd[i][1]; c += rd[i][2];
      d = fmaxf(d, rf2[i][0]); e = fmaxf(e, rf2[i][1]);
    }
    pS[(size_t)t * 3 + 0] = a; pS[(size_t)t * 3 + 1] = b; pS[(size_t)t * 3 + 2] = c;
    pM[(size_t)t * 2 + 0] = d; pM[(size_t)t * 2 + 1] = e;
  }
}

// ---------------- final combine ----------------
__global__ __launch_bounds__(256) void k_final(const double* __restrict__ pS,
                                               const float* __restrict__ pM,
                                               int nb, float* __restrict__ out) {
  int tid = threadIdx.x;
  double s1 = 0, s2 = 0, s3 = 0; float mz = 0.f, mr = 0.f;
  for (int i = tid; i < nb; i += 256) {
    s1 += pS[(size_t)i * 3 + 0]; s2 += pS[(size_t)i * 3 + 1]; s3 += pS[(size_t)i * 3 + 2];
    mz = fmaxf(mz, pM[(size_t)i * 2 + 0]); mr = fmaxf(mr, pM[(size_t)i * 2 + 1]);
  }
#pragma unroll
  for (int m = 32; m; m >>= 1) {
    s1 += __shfl_xor(s1, m); s2 += __shfl_xor(s2, m); s3 += __shfl_xor(s3, m);
    mz = fmaxf(mz, __shfl_xor(mz, m)); mr = fmaxf(mr, __shfl_xor(mr, m));
  }
  __shared__ double rd[4][3];
  __shared__ float rf2[4][2];
  int w = tid >> 6;
  if ((tid & 63) == 0) { rd[w][0] = s1; rd[w][1] = s2; rd[w][2] = s3; rf2[w][0] = mz; rf2[w][1] = mr; }
  __syncthreads();
  if (tid == 0) {
    double a = 0, b = 0, c = 0; float d = 0.f, e = 0.f;
    for (int i = 0; i < 4; ++i) {
      a += rd[i][0]; b += rd[i][1]; c += rd[i][2];
      d = fmaxf(d, rf2[i][0]); e = fmaxf(e, rf2[i][1]);
    }
    double zm = sqrt((double)d) + 1e-8;
    double rm = sqrt((double)e) + 1e-8;
    double total = a / (zm * zm) - 2.0 * b / (zm * rm) + c / (rm * rm);
    double npairs = (double)NB * (double)(NB - 1) / 2.0;
    out[0] = (float)(total / npairs);
  }
}

extern "C" void kernel_launch(void* const* d_in, const int* in_sizes, int n_in,
                              void* d_out, int out_size, void* d_ws, size_t ws_size,
                              hipStream_t stream) {
  const float* z = (const float*)d_in[0];
  const float* rfm = (const float*)d_in[1];
  const float* x = (const float*)d_in[2];
  float* out = (float*)d_out;
  char* w = (char*)d_ws;

  float*  sqx    = (float*)(w + 0);                    // 16 KB
  float*  sqz    = (float*)(w + 16384);
  float*  sqr    = (float*)(w + 32768);
  float*  curv   = (float*)(w + 49152);
  int*    knn    = (int*)(w + 65536);                  // 160 KB
  float*  cand_d = (float*)(w + 229376);               // 5.24 MB
  int*    cand_i = (int*)(w + 5472256);                // 5.24 MB
  float*  G      = (float*)(w + 10715136);             // 900 KB
  double* pS     = (double*)(w + 11616256);            // 12.7 KB
  float*  pM     = (float*)(w + 11628928);             // 4.2 KB

  ushort* xh = (ushort*)(w + (size_t)12 * 1024 * 1024); // 8 MB
  ushort* zh = (ushort*)(w + (size_t)20 * 1024 * 1024); // 1 MB
  ushort* zl = (ushort*)(w + (size_t)21 * 1024 * 1024); // 1 MB
  ushort* rh = (ushort*)(w + (size_t)22 * 1024 * 1024); // 1 MB
  ushort* rl = (ushort*)(w + (size_t)23 * 1024 * 1024); // 1 MB
  const bool pre = ws_size >= (size_t)24 * 1024 * 1024;

  if (pre) {
    k_prep_x<<<NB, 256, 0, stream>>>(x, xh, sqx);
    k_prep_zr<<<dim3(NB * DZ / 1024, 2), 256, 0, stream>>>(z, rfm, zh, zl, rh, rl, sqz, sqr);
    k_knn<1><<<dim3(STR, NB / 128), 256, 0, stream>>>(x, xh, sqx, cand_d, cand_i);
  } else {
    k_rowsq<<<NB, 256, 0, stream>>>(x, sqx, DX);
    k_rowsq<<<NB, 256, 0, stream>>>(z, sqz, DZ);
    k_rowsq<<<NB, 256, 0, stream>>>(rfm, sqr, DZ);
    k_knn<0><<<dim3(STR, NB / 128), 256, 0, stream>>>(x, xh, sqx, cand_d, cand_i);
  }
  k_merge<<<NB / 4, 256, 0, stream>>>(cand_d, cand_i, knn);
  k_gram<<<NB, 64, 0, stream>>>(x, knn, G);
  k_jacobi<<<NB / 64, 64, 0, stream>>>(G, curv);
  if (pre) {
    k_zr<1><<<528, 256, 0, stream>>>(z, rfm, zh, zl, rh, rl, sqz, sqr, curv, pS, pM);
  } else {
    k_zr<0><<<528, 256, 0, stream>>>(z, rfm, zh, zl, rh, rl, sqz, sqr, curv, pS, pM);
  }
  k_final<<<1, 256, 0, stream>>>(pS, pM, 528, out);
}

// Round 8
// 297.520 us; speedup vs baseline: 1.3413x; 1.3413x over previous
//
#include <hip/hip_runtime.h>
#include <math.h>

#define NB 4096
#define DX 1024
#define DZ 128
#define KNN 10
#define STR 32
#define NLIST 32         /* one merged list per row per strip */
#define BKK 64           /* kNN K-tile */

typedef short short8v __attribute__((ext_vector_type(8)));
typedef float f32x4 __attribute__((ext_vector_type(4)));

#define MFMA16(a, b, c) __builtin_amdgcn_mfma_f32_16x16x32_bf16((a), (b), (c), 0, 0, 0)

__device__ __forceinline__ ushort f2bf(float f) {
  unsigned u = __float_as_uint(f);
  u += 0x7FFFu + ((u >> 16) & 1u);
  return (ushort)(u >> 16);
}
__device__ __forceinline__ float bf2f(ushort h) {
  return __uint_as_float(((unsigned)h) << 16);
}

// k_zr (BK=32, 64B rows) swizzled fragment load
__device__ __forceinline__ short8v frag_ld(const ushort* base, int row, int fg) {
  int off = (row << 6) + (fg << 4);
  off ^= (row & 7) << 4;
  return *(const short8v*)((const char*)base + off);
}

// kNN (BK=64, 128B rows): slot-permutation swizzle, pure within-row bijection
__device__ __forceinline__ int swz64(int row, int c8) {
  return (row << 7) + ((c8 ^ (row & 7)) << 4);
}
__device__ __forceinline__ short8v frag_ld64(const ushort* base, int row, int kk, int fg) {
  return *(const short8v*)((const char*)base + swz64(row, kk * 4 + fg));
}

// branchless register top-10 insert (all indices static after unroll)
#define INSERT10(td, ti, v, idx)                         \
  do {                                                   \
    if ((v) < td[KNN - 1]) {                             \
      _Pragma("unroll")                                  \
      for (int k_ = KNN - 1; k_ >= 1; --k_) {            \
        bool bk = (v) < td[k_];                          \
        bool bk1 = (v) < td[k_ - 1];                     \
        td[k_] = bk ? (bk1 ? td[k_ - 1] : (v)) : td[k_]; \
        ti[k_] = bk ? (bk1 ? ti[k_ - 1] : (idx)) : ti[k_]; \
      }                                                  \
      bool b0 = (v) < td[0];                             \
      ti[0] = b0 ? (idx) : ti[0];                        \
      td[0] = b0 ? (v) : td[0];                          \
    }                                                    \
  } while (0)

// ---------------- row sum of squares (fallback path only) ----------------
__global__ __launch_bounds__(256) void k_rowsq(const float* __restrict__ a,
                                               float* __restrict__ out, int D) {
  int row = blockIdx.x;
  const float4* p = (const float4*)(a + (size_t)row * D);
  float s = 0.f;
  for (int d = threadIdx.x; d < (D >> 2); d += 256) {
    float4 v = p[d];
    s = fmaf(v.x, v.x, s); s = fmaf(v.y, v.y, s);
    s = fmaf(v.z, v.z, s); s = fmaf(v.w, v.w, s);
  }
#pragma unroll
  for (int m = 32; m; m >>= 1) s += __shfl_xor(s, m);
  __shared__ float red[4];
  int w = threadIdx.x >> 6;
  if ((threadIdx.x & 63) == 0) red[w] = s;
  __syncthreads();
  if (threadIdx.x == 0) out[row] = red[0] + red[1] + red[2] + red[3];
}

// ---------------- fused prep for x: bf16-hi split + row sumsq ----------------
__global__ __launch_bounds__(256) void k_prep_x(const float* __restrict__ x,
                                                ushort* __restrict__ xh,
                                                float* __restrict__ sqx) {
  const int row = blockIdx.x, t = threadIdx.x;
  float4 v = ((const float4*)(x + (size_t)row * DX))[t];
  ushort4 hv;
  hv.x = f2bf(v.x); hv.y = f2bf(v.y); hv.z = f2bf(v.z); hv.w = f2bf(v.w);
  ((ushort4*)(xh + (size_t)row * DX))[t] = hv;
  float s = fmaf(v.x, v.x, fmaf(v.y, v.y, fmaf(v.z, v.z, v.w * v.w)));
#pragma unroll
  for (int m = 32; m; m >>= 1) s += __shfl_xor(s, m);
  __shared__ float red[4];
  int w = t >> 6;
  if ((t & 63) == 0) red[w] = s;
  __syncthreads();
  if (t == 0) sqx[row] = red[0] + red[1] + red[2] + red[3];
}

// ---------------- fused prep for z/ref: hi/lo split + row sumsq ----------------
__global__ __launch_bounds__(256) void k_prep_zr(const float* __restrict__ z,
                                                 const float* __restrict__ rfm,
                                                 ushort* __restrict__ zh, ushort* __restrict__ zl,
                                                 ushort* __restrict__ rh, ushort* __restrict__ rl,
                                                 float* __restrict__ sqz, float* __restrict__ sqr) {
  const float* src = blockIdx.y ? rfm : z;
  ushort* ph = blockIdx.y ? rh : zh;
  ushort* pl = blockIdx.y ? rl : zl;
  float* sq = blockIdx.y ? sqr : sqz;
  const int t = threadIdx.x;
  const size_t base = (size_t)blockIdx.x * 1024;
  float4 v = ((const float4*)(src + base))[t];
  float vv[4] = {v.x, v.y, v.z, v.w};
  ushort h[4], l[4];
#pragma unroll
  for (int e = 0; e < 4; ++e) {
    h[e] = f2bf(vv[e]);
    l[e] = f2bf(vv[e] - bf2f(h[e]));
  }
  ushort4 hv; hv.x = h[0]; hv.y = h[1]; hv.z = h[2]; hv.w = h[3];
  ushort4 lv; lv.x = l[0]; lv.y = l[1]; lv.z = l[2]; lv.w = l[3];
  ((ushort4*)(ph + base))[t] = hv;
  ((ushort4*)(pl + base))[t] = lv;
  float s = fmaf(v.x, v.x, fmaf(v.y, v.y, fmaf(v.z, v.z, v.w * v.w)));
#pragma unroll
  for (int m = 16; m; m >>= 1) s += __shfl_xor(s, m);
  if ((t & 31) == 0) sq[blockIdx.x * 8 + (t >> 5)] = s;
}

// ---------------- kNN via MFMA: one 128x128 tile per block (r6 staging) ----------------
struct SmemKNN {
  union {
    struct { ushort Ah[128 * BKK], Bh[128 * BKK]; } s;  // 16+16 KB
    float D[64 * 129];                                  // 33 KB (chunked)
  } u;
};

template<int PRE>
__global__ __launch_bounds__(256, 4) void k_knn(const float* __restrict__ x,
                                                const ushort* __restrict__ xh,
                                                const float* __restrict__ sqx,
                                                float* __restrict__ cand_d,
                                                int* __restrict__ cand_i) {
  __shared__ SmemKNN sm;
  // bijective 2D XCD swizzle: each XCD owns an 8-strip x 16-itile rectangle
  const int bid = blockIdx.y * STR + blockIdx.x;
  const int xcd = bid & 7, rr = bid >> 3;
  const int strip = (xcd & 3) * 8 + (rr & 7);
  const int itile = (xcd >> 2) * 16 + (rr >> 3);
  const int i0 = itile * 128;
  const int j0 = strip * 128;

  const int tid = threadIdx.x;
  const int lane = tid & 63, wv = tid >> 6;
  const int wr = wv >> 1, wc = wv & 1;
  const int fr = lane & 15, fg = lane >> 4;

  float td[KNN];
  int ti[KNN];
#pragma unroll
  for (int k = 0; k < KNN; ++k) { td[k] = 3.0e38f; ti[k] = 0; }
  const int my_chunk = tid >> 7;
  const int t2 = tid & 127;
  const int srow = t2 >> 1;
  const int cbase = (tid & 1) * 64;

  f32x4 acc[4][4];
  const f32x4 zv4 = {0.f, 0.f, 0.f, 0.f};
#pragma unroll
  for (int m = 0; m < 4; ++m)
#pragma unroll
    for (int n = 0; n < 4; ++n) acc[m][n] = zv4;

  for (int kc = 0; kc < DX; kc += BKK) {
    __syncthreads();
    if (PRE) {
#pragma unroll
      for (int l = 0; l < 4; ++l) {
        int idx = tid + l * 256;            // 0..1023
        int row = idx >> 3, c8 = idx & 7;
        int off = swz64(row, c8);
        *(uint4*)((char*)sm.u.s.Ah + off) =
            *(const uint4*)(xh + (size_t)(i0 + row) * DX + kc + c8 * 8);
        *(uint4*)((char*)sm.u.s.Bh + off) =
            *(const uint4*)(xh + (size_t)(j0 + row) * DX + kc + c8 * 8);
      }
    } else {
#pragma unroll
      for (int l = 0; l < 4; ++l) {
        int idx = tid + l * 256;
        int row = idx >> 3, c8 = idx & 7;
        int off = swz64(row, c8);
        const float* pa = &x[(size_t)(i0 + row) * DX + kc + c8 * 8];
        const float* pb = &x[(size_t)(j0 + row) * DX + kc + c8 * 8];
        float4 a1 = *(const float4*)pa, a2 = *(const float4*)(pa + 4);
        float4 b1 = *(const float4*)pb, b2 = *(const float4*)(pb + 4);
        uint4 pva, pvb;
        pva.x = (unsigned)f2bf(a1.x) | ((unsigned)f2bf(a1.y) << 16);
        pva.y = (unsigned)f2bf(a1.z) | ((unsigned)f2bf(a1.w) << 16);
        pva.z = (unsigned)f2bf(a2.x) | ((unsigned)f2bf(a2.y) << 16);
        pva.w = (unsigned)f2bf(a2.z) | ((unsigned)f2bf(a2.w) << 16);
        pvb.x = (unsigned)f2bf(b1.x) | ((unsigned)f2bf(b1.y) << 16);
        pvb.y = (unsigned)f2bf(b1.z) | ((unsigned)f2bf(b1.w) << 16);
        pvb.z = (unsigned)f2bf(b2.x) | ((unsigned)f2bf(b2.y) << 16);
        pvb.w = (unsigned)f2bf(b2.z) | ((unsigned)f2bf(b2.w) << 16);
        *(uint4*)((char*)sm.u.s.Ah + off) = pva;
        *(uint4*)((char*)sm.u.s.Bh + off) = pvb;
      }
    }
    __syncthreads();
#pragma unroll
    for (int kk = 0; kk < 2; ++kk) {
      short8v fa[4];
#pragma unroll
      for (int m = 0; m < 4; ++m)
        fa[m] = frag_ld64(sm.u.s.Ah, wr * 64 + m * 16 + fr, kk, fg);
#pragma unroll
      for (int n = 0; n < 4; ++n) {
        short8v fb = frag_ld64(sm.u.s.Bh, wc * 64 + n * 16 + fr, kk, fg);
#pragma unroll
        for (int m = 0; m < 4; ++m)
          acc[m][n] = MFMA16(fa[m], fb, acc[m][n]);
      }
    }
  }
  __syncthreads();
  // chunked epilogue: two 64-row passes through the 33 KB D buffer
#pragma unroll
  for (int chunk = 0; chunk < 2; ++chunk) {
    if (wr == chunk) {
#pragma unroll
      for (int m = 0; m < 4; ++m)
#pragma unroll
        for (int n = 0; n < 4; ++n)
#pragma unroll
          for (int r = 0; r < 4; ++r) {
            int rl = m * 16 + fg * 4 + r;
            int cl = wc * 64 + n * 16 + fr;
            int gi = i0 + chunk * 64 + rl, gj = j0 + cl;
            float v = sqx[gi] + sqx[gj] - 2.f * acc[m][n][r];
            sm.u.D[rl * 129 + cl] = (gi == gj) ? 3.0e38f : v;
          }
    }
    __syncthreads();
    if (my_chunk == chunk) {
#pragma unroll 4
      for (int c = 0; c < 64; ++c) {
        float v = sm.u.D[srow * 129 + cbase + c];
        int idx = j0 + cbase + c;
        INSERT10(td, ti, v, idx);
      }
    }
    __syncthreads();
  }
  // pair-merge the two half-row lists via shuffle (snapshot first!)
  {
    float pd[KNN]; int pi[KNN];
#pragma unroll
    for (int l = 0; l < KNN; ++l) {
      pd[l] = __shfl_xor(td[l], 1);
      pi[l] = __shfl_xor(ti[l], 1);
    }
#pragma unroll
    for (int l = 0; l < KNN; ++l) INSERT10(td, ti, pd[l], pi[l]);
    if ((tid & 1) == 0) {
      int row = i0 + my_chunk * 64 + srow;
#pragma unroll
      for (int l = 0; l < KNN; ++l) {
        cand_d[((size_t)row * NLIST + strip) * KNN + l] = td[l];
        cand_i[((size_t)row * NLIST + strip) * KNN + l] = ti[l];
      }
    }
  }
}

// ------- fused merge (wave butterfly argmin) + Gram matrix: one wave per point -------
__global__ __launch_bounds__(64) void k_mergegram(const float* __restrict__ cand_d,
                                                  const int* __restrict__ cand_i,
                                                  const float* __restrict__ x,
                                                  float* __restrict__ G) {
  const int pt = blockIdx.x;
  const int lane = threadIdx.x;
  // --- merge: 32 sorted lists -> global top-10, all lanes end with the index ---
  float v[KNN]; int jx[KNN];
  const float* cd = cand_d + ((size_t)pt * NLIST + lane) * KNN;
  const int* ci = cand_i + ((size_t)pt * NLIST + lane) * KNN;
  const bool act = lane < NLIST;
#pragma unroll
  for (int l = 0; l < KNN; ++l) {
    v[l] = act ? cd[l] : 3.0e38f;
    jx[l] = act ? ci[l] : 0;
  }
  const float4* nb[KNN];
#pragma unroll
  for (int k = 0; k < KNN; ++k) {
    float bv = v[0]; int bj = jx[0]; int bl = lane;
#pragma unroll
    for (int m = 1; m < 64; m <<= 1) {
      float ov = __shfl_xor(bv, m);
      int oj = __shfl_xor(bj, m);
      int ol = __shfl_xor(bl, m);
      bool take = ov < bv;
      bv = take ? ov : bv; bj = take ? oj : bj; bl = take ? ol : bl;
    }
    nb[k] = (const float4*)(x + (size_t)bj * DX);   // all lanes agree on bj
    if (lane == bl) {
#pragma unroll
      for (int l = 0; l < KNN - 1; ++l) { v[l] = v[l + 1]; jx[l] = jx[l + 1]; }
      v[KNN - 1] = 3.0e38f;
    }
  }
  // --- Gram of centered neighbors ---
  float P[55];
  float U[KNN];
  float q = 0.f;
#pragma unroll
  for (int c = 0; c < 55; ++c) P[c] = 0.f;
#pragma unroll
  for (int a = 0; a < KNN; ++a) U[a] = 0.f;
  for (int d4 = lane; d4 < DX / 4; d4 += 64) {
    float4 n4[KNN];
#pragma unroll
    for (int a = 0; a < KNN; ++a) n4[a] = nb[a][d4];
#pragma unroll
    for (int e = 0; e < 4; ++e) {
      float n[KNN];
#pragma unroll
      for (int a = 0; a < KNN; ++a) n[a] = ((const float*)&n4[a])[e];
      float m = 0.f;
#pragma unroll
      for (int a = 0; a < KNN; ++a) m += n[a];
      m *= 0.1f;
      q = fmaf(m, m, q);
#pragma unroll
      for (int a = 0; a < KNN; ++a) U[a] = fmaf(n[a], m, U[a]);
      int c = 0;
#pragma unroll
      for (int a = 0; a < KNN; ++a)
#pragma unroll
        for (int b = a; b < KNN; ++b) { P[c] = fmaf(n[a], n[b], P[c]); ++c; }
    }
  }
#pragma unroll
  for (int c = 0; c < 55; ++c)
#pragma unroll
    for (int m2 = 32; m2; m2 >>= 1) P[c] += __shfl_xor(P[c], m2);
#pragma unroll
  for (int a = 0; a < KNN; ++a)
#pragma unroll
    for (int m2 = 32; m2; m2 >>= 1) U[a] += __shfl_xor(U[a], m2);
#pragma unroll
  for (int m2 = 32; m2; m2 >>= 1) q += __shfl_xor(q, m2);
  if (lane == 0) {
    int c = 0;
    for (int a = 0; a < KNN; ++a)
      for (int b = a; b < KNN; ++b) { G[(size_t)pt * 55 + c] = P[c] - U[a] - U[b] + q; ++c; }
  }
}

// ---------------- Jacobi eigenvalues of 10x10 in registers ---------------
__device__ __forceinline__ constexpr int IJ(int a, int b) {
  return (a <= b) ? (10 * a - (a * (a - 1)) / 2 + (b - a))
                  : (10 * b - (b * (b - 1)) / 2 + (a - b));
}

#define ROTPQ(p, q)                                                  \
  {                                                                  \
    float apq = M[IJ((p), (q))];                                     \
    float app = M[IJ((p), (p))], aqq = M[IJ((q), (q))];              \
    float theta = (aqq - app) / (2.f * apq);                         \
    float t = 1.f / (fabsf(theta) + sqrtf(fmaf(theta, theta, 1.f))); \
    t = (theta < 0.f) ? -t : t;                                      \
    t = (apq == 0.f) ? 0.f : t;                                      \
    float cc = 1.f / sqrtf(fmaf(t, t, 1.f));                         \
    float ss = t * cc;                                               \
    _Pragma("unroll")                                                \
    for (int r_ = 0; r_ < KNN; ++r_) {                               \
      if (r_ == (p) || r_ == (q)) continue;                          \
      float vrp = M[IJ(r_, (p))];                                    \
      float vrq = M[IJ(r_, (q))];                                    \
      M[IJ(r_, (p))] = cc * vrp - ss * vrq;                          \
      M[IJ(r_, (q))] = ss * vrp + cc * vrq;                          \
    }                                                                \
    M[IJ((p), (p))] = app - t * apq;                                 \
    M[IJ((q), (q))] = aqq + t * apq;                                 \
    M[IJ((p), (q))] = 0.f;                                           \
  }

#define NSWEEP 7
__global__ __launch_bounds__(64) void k_jacobi(const float* __restrict__ G,
                                               float* __restrict__ curv) {
  const int pt = blockIdx.x * 64 + threadIdx.x;
  float M[55];
#pragma unroll
  for (int c = 0; c < 55; ++c) M[c] = G[(size_t)pt * 55 + c];

#pragma unroll
  for (int sweep = 0; sweep < NSWEEP; ++sweep) {
#pragma unroll
    for (int rd = 0; rd < 9; ++rd) {
      ROTPQ(9, rd);
      ROTPQ((rd + 1) % 9, (rd + 8) % 9);
      ROTPQ((rd + 2) % 9, (rd + 7) % 9);
      ROTPQ((rd + 3) % 9, (rd + 6) % 9);
      ROTPQ((rd + 4) % 9, (rd + 5) % 9);
    }
  }

  float lmax = 0.f, ssum = 0.f;
#pragma unroll
  for (int a = 0; a < KNN; ++a) {
    float l = fmaxf(M[IJ(a, a)], 0.f);
    lmax = fmaxf(lmax, l);
    ssum += sqrtf(l);
  }
  curv[pt] = 1.f - sqrtf(lmax) / (ssum + 1e-8f);
}

// ---------------- fused z/ref upper-triangle pass (MFMA, hi+lo) ----------------
template<int PRE>
__global__ __launch_bounds__(256, 2) void k_zr(const float* __restrict__ z,
                                               const float* __restrict__ rfm,
                                               const ushort* __restrict__ zh,
                                               const ushort* __restrict__ zl,
                                               const ushort* __restrict__ rh,
                                               const ushort* __restrict__ rl,
                                               const float* __restrict__ sqz,
                                               const float* __restrict__ sqr,
                                               const float* __restrict__ curv,
                                               double* __restrict__ pS,
                                               float* __restrict__ pM) {
  __shared__ struct { ushort Ah[4096], Al[4096], Bh[4096], Bl[4096]; } s;
  const int t = blockIdx.x;
  int ib = 0, base = 0;
  while (base + (32 - ib) <= t) { base += 32 - ib; ++ib; }
  const int jb = ib + (t - base);
  const int i0 = ib * 128, j0 = jb * 128;
  const int tid = threadIdx.x;
  const int lane = tid & 63, wv = tid >> 6;
  const int wr = wv >> 1, wc = wv & 1;
  const int fr = lane & 15, fg = lane >> 4;

  f32x4 zacc[4][4], racc[4][4];
  const f32x4 zv = {0.f, 0.f, 0.f, 0.f};
#pragma unroll
  for (int m = 0; m < 4; ++m)
#pragma unroll
    for (int n = 0; n < 4; ++n) { zacc[m][n] = zv; racc[m][n] = zv; }

#pragma unroll
  for (int mat = 0; mat < 2; ++mat) {
    const float* P = mat ? rfm : z;
    const ushort* Ph = mat ? rh : zh;
    const ushort* Pl = mat ? rl : zl;
    for (int kc = 0; kc < DZ; kc += 32) {
      __syncthreads();
      if (PRE) {
#pragma unroll
        for (int l = 0; l < 2; ++l) {
          int idx = tid + l * 256;
          int row = idx >> 2, c8 = idx & 3;
          int off = (row << 6) + (c8 << 4);
          off ^= (row & 7) << 4;
          size_t ga = (size_t)(i0 + row) * DZ + kc + c8 * 8;
          size_t gb = (size_t)(j0 + row) * DZ + kc + c8 * 8;
          *(uint4*)((char*)s.Ah + off) = *(const uint4*)(Ph + ga);
          *(uint4*)((char*)s.Al + off) = *(const uint4*)(Pl + ga);
          *(uint4*)((char*)s.Bh + off) = *(const uint4*)(Ph + gb);
          *(uint4*)((char*)s.Bl + off) = *(const uint4*)(Pl + gb);
        }
      } else {
#pragma unroll
        for (int l = 0; l < 4; ++l) {
          int idx = tid + l * 256;
          int row = idx >> 3, c4 = idx & 7;
          int off = (row << 6) + (c4 << 3);
          off ^= (row & 7) << 4;
          float4 va = *(const float4*)&P[(size_t)(i0 + row) * DZ + kc + c4 * 4];
          float4 vb = *(const float4*)&P[(size_t)(j0 + row) * DZ + kc + c4 * 4];
          float av[4] = {va.x, va.y, va.z, va.w};
          float bv[4] = {vb.x, vb.y, vb.z, vb.w};
          ushort ah4[4], al4[4], bh4[4], bl4[4];
#pragma unroll
          for (int e = 0; e < 4; ++e) {
            ah4[e] = f2bf(av[e]); al4[e] = f2bf(av[e] - bf2f(ah4[e]));
            bh4[e] = f2bf(bv[e]); bl4[e] = f2bf(bv[e] - bf2f(bh4[e]));
          }
          uint2 p;
          p.x = (unsigned)ah4[0] | ((unsigned)ah4[1] << 16);
          p.y = (unsigned)ah4[2] | ((unsigned)ah4[3] << 16);
          *(uint2*)((char*)s.Ah + off) = p;
          p.x = (unsigned)al4[0] | ((unsigned)al4[1] << 16);
          p.y = (unsigned)al4[2] | ((unsigned)al4[3] << 16);
          *(uint2*)((char*)s.Al + off) = p;
          p.x = (unsigned)bh4[0] | ((unsigned)bh4[1] << 16);
          p.y = (unsigned)bh4[2] | ((unsigned)bh4[3] << 16);
          *(uint2*)((char*)s.Bh + off) = p;
          p.x = (unsigned)bl4[0] | ((unsigned)bl4[1] << 16);
          p.y = (unsigned)bl4[2] | ((unsigned)bl4[3] << 16);
          *(uint2*)((char*)s.Bl + off) = p;
        }
      }
      __syncthreads();
      short8v fah[4], fal[4];
#pragma unroll
      for (int m = 0; m < 4; ++m) {
        int r = wr * 64 + m * 16 + fr;
        fah[m] = frag_ld(s.Ah, r, fg);
        fal[m] = frag_ld(s.Al, r, fg);
      }
#pragma unroll
      for (int n = 0; n < 4; ++n) {
        int r = wc * 64 + n * 16 + fr;
        short8v fbh = frag_ld(s.Bh, r, fg);
        short8v fbl = frag_ld(s.Bl, r, fg);
#pragma unroll
        for (int m = 0; m < 4; ++m) {
          if (mat == 0) {
            zacc[m][n] = MFMA16(fah[m], fbh, zacc[m][n]);
            zacc[m][n] = MFMA16(fah[m], fbl, zacc[m][n]);
            zacc[m][n] = MFMA16(fal[m], fbh, zacc[m][n]);
          } else {
            racc[m][n] = MFMA16(fah[m], fbh, racc[m][n]);
            racc[m][n] = MFMA16(fah[m], fbl, racc[m][n]);
            racc[m][n] = MFMA16(fal[m], fbh, racc[m][n]);
          }
        }
      }
    }
  }

  double s1 = 0, s2 = 0, s3 = 0;
  float mz = 0.f, mr = 0.f;
#pragma unroll
  for (int m = 0; m < 4; ++m)
#pragma unroll
    for (int n = 0; n < 4; ++n)
#pragma unroll
      for (int r = 0; r < 4; ++r) {
        int gi = i0 + wr * 64 + m * 16 + fg * 4 + r;
        int gj = j0 + wc * 64 + n * 16 + fr;
        if (gj > gi) {
          float z2 = fmaxf(sqz[gi] + sqz[gj] - 2.f * zacc[m][n][r], 0.f);
          float r2 = fmaxf(sqr[gi] + sqr[gj] - 2.f * racc[m][n][r], 0.f);
          float w = fmaxf(1.f - fmaxf(curv[gi], curv[gj]), 0.1f);
          s1 += (double)(w * z2);
          s3 += (double)(w * r2);
          s2 += (double)(w * sqrtf(z2 * r2));
          mz = fmaxf(mz, z2);
          mr = fmaxf(mr, r2);
        }
      }
#pragma unroll
  for (int m = 32; m; m >>= 1) {
    s1 += __shfl_xor(s1, m);
    s2 += __shfl_xor(s2, m);
    s3 += __shfl_xor(s3, m);
    mz = fmaxf(mz, __shfl_xor(mz, m));
    mr = fmaxf(mr, __shfl_xor(mr, m));
  }
  __shared__ double rd[4][3];
  __shared__ float rf2[4][2];
  int w = tid >> 6;
  if ((tid & 63) == 0) { rd[w][0] = s1; rd[w][1] = s2; rd[w][2] = s3; rf2[w][0] = mz; rf2[w][1] = mr; }
  __syncthreads();
  if (tid == 0) {
    double a = 0, b = 0, c = 0; float d = 0.f, e = 0.f;
    for (int i = 0; i < 4; ++i) {
      a += rd[i][0]; b += rd[i][1]; c += rd[i][2];
      d = fmaxf(d, rf2[i][0]); e = fmaxf(e, rf2[i][1]);
    }
    pS[(size_t)t * 3 + 0] = a; pS[(size_t)t * 3 + 1] = b; pS[(size_t)t * 3 + 2] = c;
    pM[(size_t)t * 2 + 0] = d; pM[(size_t)t * 2 + 1] = e;
  }
}

// ---------------- final combine ----------------
__global__ __launch_bounds__(256) void k_final(const double* __restrict__ pS,
                                               const float* __restrict__ pM,
                                               int nb, float* __restrict__ out) {
  int tid = threadIdx.x;
  double s1 = 0, s2 = 0, s3 = 0; float mz = 0.f, mr = 0.f;
  for (int i = tid; i < nb; i += 256) {
    s1 += pS[(size_t)i * 3 + 0]; s2 += pS[(size_t)i * 3 + 1]; s3 += pS[(size_t)i * 3 + 2];
    mz = fmaxf(mz, pM[(size_t)i * 2 + 0]); mr = fmaxf(mr, pM[(size_t)i * 2 + 1]);
  }
#pragma unroll
  for (int m = 32; m; m >>= 1) {
    s1 += __shfl_xor(s1, m); s2 += __shfl_xor(s2, m); s3 += __shfl_xor(s3, m);
    mz = fmaxf(mz, __shfl_xor(mz, m)); mr = fmaxf(mr, __shfl_xor(mr, m));
  }
  __shared__ double rd[4][3];
  __shared__ float rf2[4][2];
  int w = tid >> 6;
  if ((tid & 63) == 0) { rd[w][0] = s1; rd[w][1] = s2; rd[w][2] = s3; rf2[w][0] = mz; rf2[w][1] = mr; }
  __syncthreads();
  if (tid == 0) {
    double a = 0, b = 0, c = 0; float d = 0.f, e = 0.f;
    for (int i = 0; i < 4; ++i) {
      a += rd[i][0]; b += rd[i][1]; c += rd[i][2];
      d = fmaxf(d, rf2[i][0]); e = fmaxf(e, rf2[i][1]);
    }
    double zm = sqrt((double)d) + 1e-8;
    double rm = sqrt((double)e) + 1e-8;
    double total = a / (zm * zm) - 2.0 * b / (zm * rm) + c / (rm * rm);
    double npairs = (double)NB * (double)(NB - 1) / 2.0;
    out[0] = (float)(total / npairs);
  }
}

extern "C" void kernel_launch(void* const* d_in, const int* in_sizes, int n_in,
                              void* d_out, int out_size, void* d_ws, size_t ws_size,
                              hipStream_t stream) {
  const float* z = (const float*)d_in[0];
  const float* rfm = (const float*)d_in[1];
  const float* x = (const float*)d_in[2];
  float* out = (float*)d_out;
  char* w = (char*)d_ws;

  float*  sqx    = (float*)(w + 0);                    // 16 KB
  float*  sqz    = (float*)(w + 16384);
  float*  sqr    = (float*)(w + 32768);
  float*  curv   = (float*)(w + 49152);
  float*  cand_d = (float*)(w + 229376);               // 5.24 MB
  int*    cand_i = (int*)(w + 5472256);                // 5.24 MB
  float*  G      = (float*)(w + 10715136);             // 900 KB
  double* pS     = (double*)(w + 11616256);            // 12.7 KB
  float*  pM     = (float*)(w + 11628928);             // 4.2 KB

  ushort* xh = (ushort*)(w + (size_t)12 * 1024 * 1024); // 8 MB
  ushort* zh = (ushort*)(w + (size_t)20 * 1024 * 1024); // 1 MB
  ushort* zl = (ushort*)(w + (size_t)21 * 1024 * 1024); // 1 MB
  ushort* rh = (ushort*)(w + (size_t)22 * 1024 * 1024); // 1 MB
  ushort* rl = (ushort*)(w + (size_t)23 * 1024 * 1024); // 1 MB
  const bool pre = ws_size >= (size_t)24 * 1024 * 1024;

  if (pre) {
    k_prep_x<<<NB, 256, 0, stream>>>(x, xh, sqx);
    k_prep_zr<<<dim3(NB * DZ / 1024, 2), 256, 0, stream>>>(z, rfm, zh, zl, rh, rl, sqz, sqr);
    k_knn<1><<<dim3(STR, NB / 128), 256, 0, stream>>>(x, xh, sqx, cand_d, cand_i);
  } else {
    k_rowsq<<<NB, 256, 0, stream>>>(x, sqx, DX);
    k_rowsq<<<NB, 256, 0, stream>>>(z, sqz, DZ);
    k_rowsq<<<NB, 256, 0, stream>>>(rfm, sqr, DZ);
    k_knn<0><<<dim3(STR, NB / 128), 256, 0, stream>>>(x, xh, sqx, cand_d, cand_i);
  }
  k_mergegram<<<NB, 64, 0, stream>>>(cand_d, cand_i, x, G);
  k_jacobi<<<NB / 64, 64, 0, stream>>>(G, curv);
  if (pre) {
    k_zr<1><<<528, 256, 0, stream>>>(z, rfm, zh, zl, rh, rl, sqz, sqr, curv, pS, pM);
  } else {
    k_zr<0><<<528, 256, 0, stream>>>(z, rfm, zh, zl, rh, rl, sqz, sqr, curv, pS, pM);
  }
  k_final<<<1, 256, 0, stream>>>(pS, pM, 528, out);
}

// Round 9
// 248.219 us; speedup vs baseline: 1.6077x; 1.1986x over previous
//
#include <hip/hip_runtime.h>
#include <math.h>

#define NB 4096
#define DX 1024
#define DZ 128
#define KNN 10
#define STR 32
#define NLIST 32         /* one merged list per row per strip */
#define BKK 64           /* kNN K-tile */

typedef short short8v __attribute__((ext_vector_type(8)));
typedef float f32x4 __attribute__((ext_vector_type(4)));

#define MFMA16(a, b, c) __builtin_amdgcn_mfma_f32_16x16x32_bf16((a), (b), (c), 0, 0, 0)

__device__ __forceinline__ ushort f2bf(float f) {
  unsigned u = __float_as_uint(f);
  u += 0x7FFFu + ((u >> 16) & 1u);
  return (ushort)(u >> 16);
}
__device__ __forceinline__ float bf2f(ushort h) {
  return __uint_as_float(((unsigned)h) << 16);
}

// k_zr (BK=32, 64B rows) swizzled fragment load
__device__ __forceinline__ short8v frag_ld(const ushort* base, int row, int fg) {
  int off = (row << 6) + (fg << 4);
  off ^= (row & 7) << 4;
  return *(const short8v*)((const char*)base + off);
}

// kNN (BK=64, 128B rows): slot-permutation swizzle, pure within-row bijection
__device__ __forceinline__ int swz64(int row, int c8) {
  return (row << 7) + ((c8 ^ (row & 7)) << 4);
}
__device__ __forceinline__ short8v frag_ld64(const ushort* base, int row, int kk, int fg) {
  return *(const short8v*)((const char*)base + swz64(row, kk * 4 + fg));
}

// branchless register top-10 insert (all indices static after unroll)
#define INSERT10(td, ti, v, idx)                         \
  do {                                                   \
    if ((v) < td[KNN - 1]) {                             \
      _Pragma("unroll")                                  \
      for (int k_ = KNN - 1; k_ >= 1; --k_) {            \
        bool bk = (v) < td[k_];                          \
        bool bk1 = (v) < td[k_ - 1];                     \
        td[k_] = bk ? (bk1 ? td[k_ - 1] : (v)) : td[k_]; \
        ti[k_] = bk ? (bk1 ? ti[k_ - 1] : (idx)) : ti[k_]; \
      }                                                  \
      bool b0 = (v) < td[0];                             \
      ti[0] = b0 ? (idx) : ti[0];                        \
      td[0] = b0 ? (v) : td[0];                          \
    }                                                    \
  } while (0)

// ---------------- row sum of squares (fallback path only) ----------------
__global__ __launch_bounds__(256) void k_rowsq(const float* __restrict__ a,
                                               float* __restrict__ out, int D) {
  int row = blockIdx.x;
  const float4* p = (const float4*)(a + (size_t)row * D);
  float s = 0.f;
  for (int d = threadIdx.x; d < (D >> 2); d += 256) {
    float4 v = p[d];
    s = fmaf(v.x, v.x, s); s = fmaf(v.y, v.y, s);
    s = fmaf(v.z, v.z, s); s = fmaf(v.w, v.w, s);
  }
#pragma unroll
  for (int m = 32; m; m >>= 1) s += __shfl_xor(s, m);
  __shared__ float red[4];
  int w = threadIdx.x >> 6;
  if ((threadIdx.x & 63) == 0) red[w] = s;
  __syncthreads();
  if (threadIdx.x == 0) out[row] = red[0] + red[1] + red[2] + red[3];
}

// ---------------- fused prep for x: bf16-hi split + row sumsq ----------------
__global__ __launch_bounds__(256) void k_prep_x(const float* __restrict__ x,
                                                ushort* __restrict__ xh,
                                                float* __restrict__ sqx) {
  const int row = blockIdx.x, t = threadIdx.x;
  float4 v = ((const float4*)(x + (size_t)row * DX))[t];
  ushort4 hv;
  hv.x = f2bf(v.x); hv.y = f2bf(v.y); hv.z = f2bf(v.z); hv.w = f2bf(v.w);
  ((ushort4*)(xh + (size_t)row * DX))[t] = hv;
  float s = fmaf(v.x, v.x, fmaf(v.y, v.y, fmaf(v.z, v.z, v.w * v.w)));
#pragma unroll
  for (int m = 32; m; m >>= 1) s += __shfl_xor(s, m);
  __shared__ float red[4];
  int w = t >> 6;
  if ((t & 63) == 0) red[w] = s;
  __syncthreads();
  if (t == 0) sqx[row] = red[0] + red[1] + red[2] + red[3];
}

// ---------------- fused prep for z/ref: hi/lo split + row sumsq ----------------
__global__ __launch_bounds__(256) void k_prep_zr(const float* __restrict__ z,
                                                 const float* __restrict__ rfm,
                                                 ushort* __restrict__ zh, ushort* __restrict__ zl,
                                                 ushort* __restrict__ rh, ushort* __restrict__ rl,
                                                 float* __restrict__ sqz, float* __restrict__ sqr) {
  const float* src = blockIdx.y ? rfm : z;
  ushort* ph = blockIdx.y ? rh : zh;
  ushort* pl = blockIdx.y ? rl : zl;
  float* sq = blockIdx.y ? sqr : sqz;
  const int t = threadIdx.x;
  const size_t base = (size_t)blockIdx.x * 1024;
  float4 v = ((const float4*)(src + base))[t];
  float vv[4] = {v.x, v.y, v.z, v.w};
  ushort h[4], l[4];
#pragma unroll
  for (int e = 0; e < 4; ++e) {
    h[e] = f2bf(vv[e]);
    l[e] = f2bf(vv[e] - bf2f(h[e]));
  }
  ushort4 hv; hv.x = h[0]; hv.y = h[1]; hv.z = h[2]; hv.w = h[3];
  ushort4 lv; lv.x = l[0]; lv.y = l[1]; lv.z = l[2]; lv.w = l[3];
  ((ushort4*)(ph + base))[t] = hv;
  ((ushort4*)(pl + base))[t] = lv;
  float s = fmaf(v.x, v.x, fmaf(v.y, v.y, fmaf(v.z, v.z, v.w * v.w)));
#pragma unroll
  for (int m = 16; m; m >>= 1) s += __shfl_xor(s, m);
  if ((t & 31) == 0) sq[blockIdx.x * 8 + (t >> 5)] = s;
}

// ---------------- kNN via MFMA: one 128x128 tile per block (r6 staging) ----------------
struct SmemKNN {
  union {
    struct { ushort Ah[128 * BKK], Bh[128 * BKK]; } s;  // 16+16 KB
    float D[64 * 129];                                  // 33 KB (chunked)
  } u;
};

template<int PRE>
__global__ __launch_bounds__(256, 4) void k_knn(const float* __restrict__ x,
                                                const ushort* __restrict__ xh,
                                                const float* __restrict__ sqx,
                                                float* __restrict__ cand_d,
                                                int* __restrict__ cand_i) {
  __shared__ SmemKNN sm;
  // bijective 2D XCD swizzle: each XCD owns an 8-strip x 16-itile rectangle
  const int bid = blockIdx.y * STR + blockIdx.x;
  const int xcd = bid & 7, rr = bid >> 3;
  const int strip = (xcd & 3) * 8 + (rr & 7);
  const int itile = (xcd >> 2) * 16 + (rr >> 3);
  const int i0 = itile * 128;
  const int j0 = strip * 128;

  const int tid = threadIdx.x;
  const int lane = tid & 63, wv = tid >> 6;
  const int wr = wv >> 1, wc = wv & 1;
  const int fr = lane & 15, fg = lane >> 4;

  float td[KNN];
  int ti[KNN];
#pragma unroll
  for (int k = 0; k < KNN; ++k) { td[k] = 3.0e38f; ti[k] = 0; }
  const int my_chunk = tid >> 7;
  const int t2 = tid & 127;
  const int srow = t2 >> 1;
  const int cbase = (tid & 1) * 64;

  f32x4 acc[4][4];
  const f32x4 zv4 = {0.f, 0.f, 0.f, 0.f};
#pragma unroll
  for (int m = 0; m < 4; ++m)
#pragma unroll
    for (int n = 0; n < 4; ++n) acc[m][n] = zv4;

  for (int kc = 0; kc < DX; kc += BKK) {
    __syncthreads();
    if (PRE) {
#pragma unroll
      for (int l = 0; l < 4; ++l) {
        int idx = tid + l * 256;            // 0..1023
        int row = idx >> 3, c8 = idx & 7;
        int off = swz64(row, c8);
        *(uint4*)((char*)sm.u.s.Ah + off) =
            *(const uint4*)(xh + (size_t)(i0 + row) * DX + kc + c8 * 8);
        *(uint4*)((char*)sm.u.s.Bh + off) =
            *(const uint4*)(xh + (size_t)(j0 + row) * DX + kc + c8 * 8);
      }
    } else {
#pragma unroll
      for (int l = 0; l < 4; ++l) {
        int idx = tid + l * 256;
        int row = idx >> 3, c8 = idx & 7;
        int off = swz64(row, c8);
        const float* pa = &x[(size_t)(i0 + row) * DX + kc + c8 * 8];
        const float* pb = &x[(size_t)(j0 + row) * DX + kc + c8 * 8];
        float4 a1 = *(const float4*)pa, a2 = *(const float4*)(pa + 4);
        float4 b1 = *(const float4*)pb, b2 = *(const float4*)(pb + 4);
        uint4 pva, pvb;
        pva.x = (unsigned)f2bf(a1.x) | ((unsigned)f2bf(a1.y) << 16);
        pva.y = (unsigned)f2bf(a1.z) | ((unsigned)f2bf(a1.w) << 16);
        pva.z = (unsigned)f2bf(a2.x) | ((unsigned)f2bf(a2.y) << 16);
        pva.w = (unsigned)f2bf(a2.z) | ((unsigned)f2bf(a2.w) << 16);
        pvb.x = (unsigned)f2bf(b1.x) | ((unsigned)f2bf(b1.y) << 16);
        pvb.y = (unsigned)f2bf(b1.z) | ((unsigned)f2bf(b1.w) << 16);
        pvb.z = (unsigned)f2bf(b2.x) | ((unsigned)f2bf(b2.y) << 16);
        pvb.w = (unsigned)f2bf(b2.z) | ((unsigned)f2bf(b2.w) << 16);
        *(uint4*)((char*)sm.u.s.Ah + off) = pva;
        *(uint4*)((char*)sm.u.s.Bh + off) = pvb;
      }
    }
    __syncthreads();
#pragma unroll
    for (int kk = 0; kk < 2; ++kk) {
      short8v fa[4];
#pragma unroll
      for (int m = 0; m < 4; ++m)
        fa[m] = frag_ld64(sm.u.s.Ah, wr * 64 + m * 16 + fr, kk, fg);
#pragma unroll
      for (int n = 0; n < 4; ++n) {
        short8v fb = frag_ld64(sm.u.s.Bh, wc * 64 + n * 16 + fr, kk, fg);
#pragma unroll
        for (int m = 0; m < 4; ++m)
          acc[m][n] = MFMA16(fa[m], fb, acc[m][n]);
      }
    }
  }
  __syncthreads();
  // chunked epilogue: two 64-row passes through the 33 KB D buffer
#pragma unroll
  for (int chunk = 0; chunk < 2; ++chunk) {
    if (wr == chunk) {
#pragma unroll
      for (int m = 0; m < 4; ++m)
#pragma unroll
        for (int n = 0; n < 4; ++n)
#pragma unroll
          for (int r = 0; r < 4; ++r) {
            int rl = m * 16 + fg * 4 + r;
            int cl = wc * 64 + n * 16 + fr;
            int gi = i0 + chunk * 64 + rl, gj = j0 + cl;
            float v = sqx[gi] + sqx[gj] - 2.f * acc[m][n][r];
            sm.u.D[rl * 129 + cl] = (gi == gj) ? 3.0e38f : v;
          }
    }
    __syncthreads();
    if (my_chunk == chunk) {
#pragma unroll 4
      for (int c = 0; c < 64; ++c) {
        float v = sm.u.D[srow * 129 + cbase + c];
        int idx = j0 + cbase + c;
        INSERT10(td, ti, v, idx);
      }
    }
    __syncthreads();
  }
  // pair-merge the two half-row lists via shuffle (snapshot first!)
  {
    float pd[KNN]; int pi[KNN];
#pragma unroll
    for (int l = 0; l < KNN; ++l) {
      pd[l] = __shfl_xor(td[l], 1);
      pi[l] = __shfl_xor(ti[l], 1);
    }
#pragma unroll
    for (int l = 0; l < KNN; ++l) INSERT10(td, ti, pd[l], pi[l]);
    if ((tid & 1) == 0) {
      int row = i0 + my_chunk * 64 + srow;
#pragma unroll
      for (int l = 0; l < KNN; ++l) {
        cand_d[((size_t)row * NLIST + strip) * KNN + l] = td[l];
        cand_i[((size_t)row * NLIST + strip) * KNN + l] = ti[l];
      }
    }
  }
}

// ------- fused merge (wave butterfly argmin) + Gram matrix: one wave per point -------
__global__ __launch_bounds__(64) void k_mergegram(const float* __restrict__ cand_d,
                                                  const int* __restrict__ cand_i,
                                                  const float* __restrict__ x,
                                                  float* __restrict__ G) {
  const int pt = blockIdx.x;
  const int lane = threadIdx.x;
  // --- merge: 32 sorted lists -> global top-10, all lanes end with the index ---
  float v[KNN]; int jx[KNN];
  const float* cd = cand_d + ((size_t)pt * NLIST + lane) * KNN;
  const int* ci = cand_i + ((size_t)pt * NLIST + lane) * KNN;
  const bool act = lane < NLIST;
#pragma unroll
  for (int l = 0; l < KNN; ++l) {
    v[l] = act ? cd[l] : 3.0e38f;
    jx[l] = act ? ci[l] : 0;
  }
  const float4* nb[KNN];
#pragma unroll
  for (int k = 0; k < KNN; ++k) {
    float bv = v[0]; int bj = jx[0]; int bl = lane;
#pragma unroll
    for (int m = 1; m < 64; m <<= 1) {
      float ov = __shfl_xor(bv, m);
      int oj = __shfl_xor(bj, m);
      int ol = __shfl_xor(bl, m);
      bool take = ov < bv;
      bv = take ? ov : bv; bj = take ? oj : bj; bl = take ? ol : bl;
    }
    nb[k] = (const float4*)(x + (size_t)bj * DX);   // all lanes agree on bj
    if (lane == bl) {
#pragma unroll
      for (int l = 0; l < KNN - 1; ++l) { v[l] = v[l + 1]; jx[l] = jx[l + 1]; }
      v[KNN - 1] = 3.0e38f;
    }
  }
  // --- Gram of centered neighbors ---
  float P[55];
  float U[KNN];
  float q = 0.f;
#pragma unroll
  for (int c = 0; c < 55; ++c) P[c] = 0.f;
#pragma unroll
  for (int a = 0; a < KNN; ++a) U[a] = 0.f;
  for (int d4 = lane; d4 < DX / 4; d4 += 64) {
    float4 n4[KNN];
#pragma unroll
    for (int a = 0; a < KNN; ++a) n4[a] = nb[a][d4];
#pragma unroll
    for (int e = 0; e < 4; ++e) {
      float n[KNN];
#pragma unroll
      for (int a = 0; a < KNN; ++a) n[a] = ((const float*)&n4[a])[e];
      float m = 0.f;
#pragma unroll
      for (int a = 0; a < KNN; ++a) m += n[a];
      m *= 0.1f;
      q = fmaf(m, m, q);
#pragma unroll
      for (int a = 0; a < KNN; ++a) U[a] = fmaf(n[a], m, U[a]);
      int c = 0;
#pragma unroll
      for (int a = 0; a < KNN; ++a)
#pragma unroll
        for (int b = a; b < KNN; ++b) { P[c] = fmaf(n[a], n[b], P[c]); ++c; }
    }
  }
#pragma unroll
  for (int c = 0; c < 55; ++c)
#pragma unroll
    for (int m2 = 32; m2; m2 >>= 1) P[c] += __shfl_xor(P[c], m2);
#pragma unroll
  for (int a = 0; a < KNN; ++a)
#pragma unroll
    for (int m2 = 32; m2; m2 >>= 1) U[a] += __shfl_xor(U[a], m2);
#pragma unroll
  for (int m2 = 32; m2; m2 >>= 1) q += __shfl_xor(q, m2);
  if (lane == 0) {
    int c = 0;
    for (int a = 0; a < KNN; ++a)
      for (int b = a; b < KNN; ++b) { G[(size_t)pt * 55 + c] = P[c] - U[a] - U[b] + q; ++c; }
  }
}

// ---------------- Jacobi eigenvalues of 10x10 in registers (sequential) ---------------
__device__ __forceinline__ constexpr int IJ(int a, int b) {
  return (a <= b) ? (10 * a - (a * (a - 1)) / 2 + (b - a))
                  : (10 * b - (b * (b - 1)) / 2 + (a - b));
}

#define NSWEEP 6
__global__ __launch_bounds__(64) void k_jacobi(const float* __restrict__ G,
                                               float* __restrict__ curv) {
  const int pt = blockIdx.x * 64 + threadIdx.x;
  float M[55];
#pragma unroll
  for (int c = 0; c < 55; ++c) M[c] = G[(size_t)pt * 55 + c];

#pragma unroll
  for (int sweep = 0; sweep < NSWEEP; ++sweep) {
#pragma unroll
    for (int p = 0; p < KNN - 1; ++p) {
#pragma unroll
      for (int q = p + 1; q < KNN; ++q) {
        float apq = M[IJ(p, q)];
        float app = M[IJ(p, p)], aqq = M[IJ(q, q)];
        float theta = (aqq - app) / (2.f * apq);
        float t = 1.f / (fabsf(theta) + sqrtf(fmaf(theta, theta, 1.f)));
        t = (theta < 0.f) ? -t : t;
        t = (apq == 0.f) ? 0.f : t;
        float cc = 1.f / sqrtf(fmaf(t, t, 1.f));
        float ss = t * cc;
#pragma unroll
        for (int r = 0; r < KNN; ++r) {
          if (r == p || r == q) continue;
          float vrp = M[IJ(r, p)];
          float vrq = M[IJ(r, q)];
          M[IJ(r, p)] = cc * vrp - ss * vrq;
          M[IJ(r, q)] = ss * vrp + cc * vrq;
        }
        M[IJ(p, p)] = app - t * apq;
        M[IJ(q, q)] = aqq + t * apq;
        M[IJ(p, q)] = 0.f;
      }
    }
  }

  float lmax = 0.f, ssum = 0.f;
#pragma unroll
  for (int a = 0; a < KNN; ++a) {
    float l = fmaxf(M[IJ(a, a)], 0.f);
    lmax = fmaxf(lmax, l);
    ssum += sqrtf(l);
  }
  curv[pt] = 1.f - sqrtf(lmax) / (ssum + 1e-8f);
}

// ---------------- fused z/ref upper-triangle pass (MFMA, hi+lo) ----------------
template<int PRE>
__global__ __launch_bounds__(256, 2) void k_zr(const float* __restrict__ z,
                                               const float* __restrict__ rfm,
                                               const ushort* __restrict__ zh,
                                               const ushort* __restrict__ zl,
                                               const ushort* __restrict__ rh,
                                               const ushort* __restrict__ rl,
                                               const float* __restrict__ sqz,
                                               const float* __restrict__ sqr,
                                               const float* __restrict__ curv,
                                               double* __restrict__ pS,
                                               float* __restrict__ pM) {
  __shared__ struct { ushort Ah[4096], Al[4096], Bh[4096], Bl[4096]; } s;
  const int t = blockIdx.x;
  int ib = 0, base = 0;
  while (base + (32 - ib) <= t) { base += 32 - ib; ++ib; }
  const int jb = ib + (t - base);
  const int i0 = ib * 128, j0 = jb * 128;
  const int tid = threadIdx.x;
  const int lane = tid & 63, wv = tid >> 6;
  const int wr = wv >> 1, wc = wv & 1;
  const int fr = lane & 15, fg = lane >> 4;

  f32x4 zacc[4][4], racc[4][4];
  const f32x4 zv = {0.f, 0.f, 0.f, 0.f};
#pragma unroll
  for (int m = 0; m < 4; ++m)
#pragma unroll
    for (int n = 0; n < 4; ++n) { zacc[m][n] = zv; racc[m][n] = zv; }

#pragma unroll
  for (int mat = 0; mat < 2; ++mat) {
    const float* P = mat ? rfm : z;
    const ushort* Ph = mat ? rh : zh;
    const ushort* Pl = mat ? rl : zl;
    for (int kc = 0; kc < DZ; kc += 32) {
      __syncthreads();
      if (PRE) {
#pragma unroll
        for (int l = 0; l < 2; ++l) {
          int idx = tid + l * 256;
          int row = idx >> 2, c8 = idx & 3;
          int off = (row << 6) + (c8 << 4);
          off ^= (row & 7) << 4;
          size_t ga = (size_t)(i0 + row) * DZ + kc + c8 * 8;
          size_t gb = (size_t)(j0 + row) * DZ + kc + c8 * 8;
          *(uint4*)((char*)s.Ah + off) = *(const uint4*)(Ph + ga);
          *(uint4*)((char*)s.Al + off) = *(const uint4*)(Pl + ga);
          *(uint4*)((char*)s.Bh + off) = *(const uint4*)(Ph + gb);
          *(uint4*)((char*)s.Bl + off) = *(const uint4*)(Pl + gb);
        }
      } else {
#pragma unroll
        for (int l = 0; l < 4; ++l) {
          int idx = tid + l * 256;
          int row = idx >> 3, c4 = idx & 7;
          int off = (row << 6) + (c4 << 3);
          off ^= (row & 7) << 4;
          float4 va = *(const float4*)&P[(size_t)(i0 + row) * DZ + kc + c4 * 4];
          float4 vb = *(const float4*)&P[(size_t)(j0 + row) * DZ + kc + c4 * 4];
          float av[4] = {va.x, va.y, va.z, va.w};
          float bv[4] = {vb.x, vb.y, vb.z, vb.w};
          ushort ah4[4], al4[4], bh4[4], bl4[4];
#pragma unroll
          for (int e = 0; e < 4; ++e) {
            ah4[e] = f2bf(av[e]); al4[e] = f2bf(av[e] - bf2f(ah4[e]));
            bh4[e] = f2bf(bv[e]); bl4[e] = f2bf(bv[e] - bf2f(bh4[e]));
          }
          uint2 p;
          p.x = (unsigned)ah4[0] | ((unsigned)ah4[1] << 16);
          p.y = (unsigned)ah4[2] | ((unsigned)ah4[3] << 16);
          *(uint2*)((char*)s.Ah + off) = p;
          p.x = (unsigned)al4[0] | ((unsigned)al4[1] << 16);
          p.y = (unsigned)al4[2] | ((unsigned)al4[3] << 16);
          *(uint2*)((char*)s.Al + off) = p;
          p.x = (unsigned)bh4[0] | ((unsigned)bh4[1] << 16);
          p.y = (unsigned)bh4[2] | ((unsigned)bh4[3] << 16);
          *(uint2*)((char*)s.Bh + off) = p;
          p.x = (unsigned)bl4[0] | ((unsigned)bl4[1] << 16);
          p.y = (unsigned)bl4[2] | ((unsigned)bl4[3] << 16);
          *(uint2*)((char*)s.Bl + off) = p;
        }
      }
      __syncthreads();
      short8v fah[4], fal[4];
#pragma unroll
      for (int m = 0; m < 4; ++m) {
        int r = wr * 64 + m * 16 + fr;
        fah[m] = frag_ld(s.Ah, r, fg);
        fal[m] = frag_ld(s.Al, r, fg);
      }
#pragma unroll
      for (int n = 0; n < 4; ++n) {
        int r = wc * 64 + n * 16 + fr;
        short8v fbh = frag_ld(s.Bh, r, fg);
        short8v fbl = frag_ld(s.Bl, r, fg);
#pragma unroll
        for (int m = 0; m < 4; ++m) {
          if (mat == 0) {
            zacc[m][n] = MFMA16(fah[m], fbh, zacc[m][n]);
            zacc[m][n] = MFMA16(fah[m], fbl, zacc[m][n]);
            zacc[m][n] = MFMA16(fal[m], fbh, zacc[m][n]);
          } else {
            racc[m][n] = MFMA16(fah[m], fbh, racc[m][n]);
            racc[m][n] = MFMA16(fah[m], fbl, racc[m][n]);
            racc[m][n] = MFMA16(fal[m], fbh, racc[m][n]);
          }
        }
      }
    }
  }

  double s1 = 0, s2 = 0, s3 = 0;
  float mz = 0.f, mr = 0.f;
#pragma unroll
  for (int m = 0; m < 4; ++m)
#pragma unroll
    for (int n = 0; n < 4; ++n)
#pragma unroll
      for (int r = 0; r < 4; ++r) {
        int gi = i0 + wr * 64 + m * 16 + fg * 4 + r;
        int gj = j0 + wc * 64 + n * 16 + fr;
        if (gj > gi) {
          float z2 = fmaxf(sqz[gi] + sqz[gj] - 2.f * zacc[m][n][r], 0.f);
          float r2 = fmaxf(sqr[gi] + sqr[gj] - 2.f * racc[m][n][r], 0.f);
          float w = fmaxf(1.f - fmaxf(curv[gi], curv[gj]), 0.1f);
          s1 += (double)(w * z2);
          s3 += (double)(w * r2);
          s2 += (double)(w * sqrtf(z2 * r2));
          mz = fmaxf(mz, z2);
          mr = fmaxf(mr, r2);
        }
      }
#pragma unroll
  for (int m = 32; m; m >>= 1) {
    s1 += __shfl_xor(s1, m);
    s2 += __shfl_xor(s2, m);
    s3 += __shfl_xor(s3, m);
    mz = fmaxf(mz, __shfl_xor(mz, m));
    mr = fmaxf(mr, __shfl_xor(mr, m));
  }
  __shared__ double rd[4][3];
  __shared__ float rf2[4][2];
  int w = tid >> 6;
  if ((tid & 63) == 0) { rd[w][0] = s1; rd[w][1] = s2; rd[w][2] = s3; rf2[w][0] = mz; rf2[w][1] = mr; }
  __syncthreads();
  if (tid == 0) {
    double a = 0, b = 0, c = 0; float d = 0.f, e = 0.f;
    for (int i = 0; i < 4; ++i) {
      a += rd[i][0]; b += rd[i][1]; c += rd[i][2];
      d = fmaxf(d, rf2[i][0]); e = fmaxf(e, rf2[i][1]);
    }
    pS[(size_t)t * 3 + 0] = a; pS[(size_t)t * 3 + 1] = b; pS[(size_t)t * 3 + 2] = c;
    pM[(size_t)t * 2 + 0] = d; pM[(size_t)t * 2 + 1] = e;
  }
}

// ---------------- final combine ----------------
__global__ __launch_bounds__(256) void k_final(const double* __restrict__ pS,
                                               const float* __restrict__ pM,
                                               int nb, float* __restrict__ out) {
  int tid = threadIdx.x;
  double s1 = 0, s2 = 0, s3 = 0; float mz = 0.f, mr = 0.f;
  for (int i = tid; i < nb; i += 256) {
    s1 += pS[(size_t)i * 3 + 0]; s2 += pS[(size_t)i * 3 + 1]; s3 += pS[(size_t)i * 3 + 2];
    mz = fmaxf(mz, pM[(size_t)i * 2 + 0]); mr = fmaxf(mr, pM[(size_t)i * 2 + 1]);
  }
#pragma unroll
  for (int m = 32; m; m >>= 1) {
    s1 += __shfl_xor(s1, m); s2 += __shfl_xor(s2, m); s3 += __shfl_xor(s3, m);
    mz = fmaxf(mz, __shfl_xor(mz, m)); mr = fmaxf(mr, __shfl_xor(mr, m));
  }
  __shared__ double rd[4][3];
  __shared__ float rf2[4][2];
  int w = tid >> 6;
  if ((tid & 63) == 0) { rd[w][0] = s1; rd[w][1] = s2; rd[w][2] = s3; rf2[w][0] = mz; rf2[w][1] = mr; }
  __syncthreads();
  if (tid == 0) {
    double a = 0, b = 0, c = 0; float d = 0.f, e = 0.f;
    for (int i = 0; i < 4; ++i) {
      a += rd[i][0]; b += rd[i][1]; c += rd[i][2];
      d = fmaxf(d, rf2[i][0]); e = fmaxf(e, rf2[i][1]);
    }
    double zm = sqrt((double)d) + 1e-8;
    double rm = sqrt((double)e) + 1e-8;
    double total = a / (zm * zm) - 2.0 * b / (zm * rm) + c / (rm * rm);
    double npairs = (double)NB * (double)(NB - 1) / 2.0;
    out[0] = (float)(total / npairs);
  }
}

extern "C" void kernel_launch(void* const* d_in, const int* in_sizes, int n_in,
                              void* d_out, int out_size, void* d_ws, size_t ws_size,
                              hipStream_t stream) {
  const float* z = (const float*)d_in[0];
  const float* rfm = (const float*)d_in[1];
  const float* x = (const float*)d_in[2];
  float* out = (float*)d_out;
  char* w = (char*)d_ws;

  float*  sqx    = (float*)(w + 0);                    // 16 KB
  float*  sqz    = (float*)(w + 16384);
  float*  sqr    = (float*)(w + 32768);
  float*  curv   = (float*)(w + 49152);
  float*  cand_d = (float*)(w + 229376);               // 5.24 MB
  int*    cand_i = (int*)(w + 5472256);                // 5.24 MB
  float*  G      = (float*)(w + 10715136);             // 900 KB
  double* pS     = (double*)(w + 11616256);            // 12.7 KB
  float*  pM     = (float*)(w + 11628928);             // 4.2 KB

  ushort* xh = (ushort*)(w + (size_t)12 * 1024 * 1024); // 8 MB
  ushort* zh = (ushort*)(w + (size_t)20 * 1024 * 1024); // 1 MB
  ushort* zl = (ushort*)(w + (size_t)21 * 1024 * 1024); // 1 MB
  ushort* rh = (ushort*)(w + (size_t)22 * 1024 * 1024); // 1 MB
  ushort* rl = (ushort*)(w + (size_t)23 * 1024 * 1024); // 1 MB
  const bool pre = ws_size >= (size_t)24 * 1024 * 1024;

  if (pre) {
    k_prep_x<<<NB, 256, 0, stream>>>(x, xh, sqx);
    k_prep_zr<<<dim3(NB * DZ / 1024, 2), 256, 0, stream>>>(z, rfm, zh, zl, rh, rl, sqz, sqr);
    k_knn<1><<<dim3(STR, NB / 128), 256, 0, stream>>>(x, xh, sqx, cand_d, cand_i);
  } else {
    k_rowsq<<<NB, 256, 0, stream>>>(x, sqx, DX);
    k_rowsq<<<NB, 256, 0, stream>>>(z, sqz, DZ);
    k_rowsq<<<NB, 256, 0, stream>>>(rfm, sqr, DZ);
    k_knn<0><<<dim3(STR, NB / 128), 256, 0, stream>>>(x, xh, sqx, cand_d, cand_i);
  }
  k_mergegram<<<NB, 64, 0, stream>>>(cand_d, cand_i, x, G);
  k_jacobi<<<NB / 64, 64, 0, stream>>>(G, curv);
  if (pre) {
    k_zr<1><<<528, 256, 0, stream>>>(z, rfm, zh, zl, rh, rl, sqz, sqr, curv, pS, pM);
  } else {
    k_zr<0><<<528, 256, 0, stream>>>(z, rfm, zh, zl, rh, rl, sqz, sqr, curv, pS, pM);
  }
  k_final<<<1, 256, 0, stream>>>(pS, pM, 528, out);
}